// Round 4
// baseline (45.415 us; speedup 1.0000x reference)
//
#include <hip/hip_runtime.h>
#include <math.h>

// Problem constants:
//   x:  (256, 197, 384) f32   — row 0 is CLS, rows 1..196 are "nodes"
//   ea: (256, 196, 384) f32
//   out:(256, 50, 384)  f32   — [CLS, 49 selected nodes in ascending-score order]
#define NB      256
#define NNODES  196
#define NC      384
#define SEQ     197
#define START   147          // 196//4*3
#define KEEP    49
#define OUTROWS 50
#define C4      96           // NC/4 float4 columns

// K1: column partial sums of ea
#define NCH     7            // chunks per batch
#define RPC     28           // rows per chunk (7*28 = 196)

// K2: scores
#define QCH     6            // node-chunks per batch
#define NPQ     33           // nodes per chunk (6*33 = 198 >= 196, guarded)

// ws layout: partials f32 [NB][NCH][NC]  then  scores f32 [NB][NNODES]
#define WS_PARTIALS_ELEMS  ((size_t)NB * NCH * NC)      // 688,128 floats (2.75 MB)
#define WS_SCORES_OFF      WS_PARTIALS_ELEMS

// ---- K1: per-(batch,chunk) column sums over 28 rows ----------------------
__global__ __launch_bounds__(384)
void k1_colsum(const float* __restrict__ ea, float* __restrict__ partials) {
    __shared__ double acc[4][NC];                 // 12 KB
    const int bid = blockIdx.x;                   // b*NCH + k
    const int b   = bid / NCH;
    const int k   = bid % NCH;
    const int tid = threadIdx.x;                  // 0..383
    const int c4  = tid % C4;
    const int rg  = tid / C4;                     // 0..3

    const float4* p = (const float4*)(ea + (size_t)b * NNODES * NC) + c4;
    double ax = 0.0, ay = 0.0, az = 0.0, aw = 0.0;
    #pragma unroll
    for (int i = 0; i < 7; ++i) {                 // rows k*28 + rg + 4*i
        int row = k * RPC + rg + 4 * i;
        float4 v = p[(size_t)row * C4];           // coalesced
        ax += v.x; ay += v.y; az += v.z; aw += v.w;
    }
    acc[rg][4 * c4 + 0] = ax;
    acc[rg][4 * c4 + 1] = ay;
    acc[rg][4 * c4 + 2] = az;
    acc[rg][4 * c4 + 3] = aw;
    __syncthreads();
    // 384 threads = 384 channels: fixed-order reduce (deterministic)
    double s = acc[0][tid] + acc[1][tid] + acc[2][tid] + acc[3][tid];
    partials[(size_t)bid * NC + tid] = (float)s;
}

// ---- K2: rebuild imp, then wave-per-node dot scores ----------------------
__global__ __launch_bounds__(384)
void k2_scores(const float* __restrict__ x, const float* __restrict__ partials,
               float* __restrict__ scores) {
    __shared__ alignas(16) float imp[NC];
    const int bid = blockIdx.x;                   // b*QCH + q
    const int b   = bid / QCH;
    const int q   = bid % QCH;
    const int tid = threadIdx.x;

    {   // imp[c] = sigmoid(mean): fixed k-order double sum (deterministic)
        double s = 0.0;
        #pragma unroll
        for (int k = 0; k < NCH; ++k)
            s += (double)partials[((size_t)b * NCH + k) * NC + tid];
        float m = (float)(s * (1.0 / (double)NNODES));
        imp[tid] = 1.0f / (1.0f + expf(-m));
    }
    __syncthreads();

    const int wave = tid >> 6;                    // 0..5
    const int lane = tid & 63;
    const float* nodes = x + ((size_t)b * SEQ + 1) * NC;
    const float2* imp2 = (const float2*)imp;

    float2 w[3];
    #pragma unroll
    for (int j = 0; j < 3; ++j) w[j] = imp2[lane + 64 * j];

    const int nend = (q * NPQ + NPQ < NNODES) ? q * NPQ + NPQ : NNODES;
    for (int n = q * NPQ + wave; n < nend; n += 6) {
        const float2* row2 = (const float2*)(nodes + (size_t)n * NC);
        double acc = 0.0;
        #pragma unroll
        for (int j = 0; j < 3; ++j) {
            float2 v = row2[lane + 64 * j];       // coalesced
            acc += (double)v.x * (double)w[j].x + (double)v.y * (double)w[j].y;
        }
        #pragma unroll
        for (int off = 32; off > 0; off >>= 1)
            acc += __shfl_xor(acc, off);
        if (lane == 0) scores[(size_t)b * NNODES + n] = (float)acc;
    }
}

// ---- K3: rank + gather ---------------------------------------------------
__global__ __launch_bounds__(960)
void k3_rank_gather(const float* __restrict__ x, const float* __restrict__ scores,
                    float* __restrict__ out) {
    __shared__ float sc[NNODES];
    __shared__ int   sel[KEEP];
    const int b   = blockIdx.x;
    const int tid = threadIdx.x;                  // 0..959

    if (tid < NNODES) sc[tid] = scores[(size_t)b * NNODES + tid];
    __syncthreads();

    if (tid < NNODES) {
        const float s = sc[tid];
        int rank = 0;
        for (int m = 0; m < NNODES; ++m) {
            const float sm = sc[m];
            rank += (sm < s) || (sm == s && m < tid);   // stable tie-break
        }
        if (rank >= START) sel[rank - START] = tid;
    }
    __syncthreads();

    const int jg = tid / C4;                      // 0..9
    const int c4 = tid % C4;
    const float* nodes   = x + ((size_t)b * SEQ + 1) * NC;
    const float4* nodes4 = (const float4*)nodes;
    const float4* cls4   = (const float4*)(x + (size_t)b * SEQ * NC);
    float4* out4         = (float4*)(out + (size_t)b * OUTROWS * NC);
    #pragma unroll
    for (int it = 0; it < 5; ++it) {
        int j = jg + 10 * it;                     // 0..49
        const float4* src = (j == 0) ? cls4 : (nodes4 + (size_t)sel[j - 1] * C4);
        out4[(size_t)j * C4 + c4] = src[c4];
    }
}

extern "C" void kernel_launch(void* const* d_in, const int* in_sizes, int n_in,
                              void* d_out, int out_size, void* d_ws, size_t ws_size,
                              hipStream_t stream) {
    const float* x  = (const float*)d_in[0];
    const float* ea = (const float*)d_in[1];
    float* out      = (float*)d_out;
    float* partials = (float*)d_ws;                          // 2.75 MB
    float* scores   = (float*)d_ws + WS_SCORES_OFF;          // +200 KB

    hipLaunchKernelGGL(k1_colsum,      dim3(NB * NCH), dim3(384), 0, stream, ea, partials);
    hipLaunchKernelGGL(k2_scores,      dim3(NB * QCH), dim3(384), 0, stream, x, partials, scores);
    hipLaunchKernelGGL(k3_rank_gather, dim3(NB),       dim3(960), 0, stream, x, scores, out);
}

// Round 5
// 39.602 us; speedup vs baseline: 1.1468x; 1.1468x over previous
//
#include <hip/hip_runtime.h>
#include <math.h>

// Problem constants:
//   x:  (256, 197, 384) f32   — row 0 is CLS, rows 1..196 are "nodes"
//   ea: (256, 196, 384) f32
//   out:(256, 50, 384)  f32   — [CLS, 49 selected nodes in ascending-score order]
#define NB      256
#define NNODES  196
#define NC      384
#define SEQ     197
#define START   147          // 196//4*3
#define KEEP    49
#define OUTROWS 50

#define NT      960          // 15 waves, 1 block per batch (1 block/CU)
#define NWAVE   15
#define RG      10           // row-groups in phase 1
#define C4      96           // NC/4 float4 columns
#define NPW     14           // nodes per wave strip (15*14 = 210 >= 196)

__global__ __launch_bounds__(NT)
void pooling_block_kernel(const float* __restrict__ x,
                          const float* __restrict__ ea,
                          float* __restrict__ out) {
    __shared__ double partial[RG][NC];            // 30 KB
    __shared__ alignas(16) float imp[NC];
    __shared__ float scores[NNODES];
    __shared__ int   sel[KEEP];

    const int b    = blockIdx.x;
    const int tid  = threadIdx.x;                 // 0..959
    const int wave = tid >> 6;                    // 0..14
    const int lane = tid & 63;
    const int wbase = wave * NPW;
    const float* nodes = x + ((size_t)b * SEQ + 1) * NC;  // skip CLS

    // ---- Prefetch: chunk-0 node rows (7 per wave) into registers.
    // These loads have no dependency on phase 1; issuing them first puts
    // the x-stream and the ea-stream in flight CONCURRENTLY.
    float2 vv0[7][3];
    #pragma unroll
    for (int i = 0; i < 7; ++i) {
        int n  = wbase + i;
        int nn = n < NNODES ? n : NNODES - 1;     // clamp (in-bounds)
        const float2* row2 = (const float2*)(nodes + (size_t)nn * NC);
        #pragma unroll
        for (int j = 0; j < 3; ++j) vv0[i][j] = row2[lane + 64 * j];
    }

    // ---- Phase 1: per-channel mean over 196 rows of ea (round-2 form) ----
    {
        const int rg = tid / C4;                  // 0..9
        const int c4 = tid % C4;
        const float4* p = (const float4*)(ea + (size_t)b * NNODES * NC);
        double ax = 0.0, ay = 0.0, az = 0.0, aw = 0.0;
        for (int row = rg; row < NNODES; row += RG) {
            float4 v = p[(size_t)row * C4 + c4];  // coalesced
            ax += v.x; ay += v.y; az += v.z; aw += v.w;
        }
        partial[rg][4 * c4 + 0] = ax;
        partial[rg][4 * c4 + 1] = ay;
        partial[rg][4 * c4 + 2] = az;
        partial[rg][4 * c4 + 3] = aw;
    }
    __syncthreads();
    if (tid < NC) {
        double s = 0.0;
        #pragma unroll
        for (int rg = 0; rg < RG; ++rg) s += partial[rg][tid];
        float m = (float)(s * (1.0 / (double)NNODES));
        imp[tid] = 1.0f / (1.0f + expf(-m));
    }
    __syncthreads();

    // ---- Phase 2a: dots for the prefetched chunk (registers) ----
    const float2* imp2 = (const float2*)imp;
    float2 w[3];
    #pragma unroll
    for (int j = 0; j < 3; ++j) w[j] = imp2[lane + 64 * j];

    #pragma unroll
    for (int i = 0; i < 7; ++i) {
        double acc = 0.0;
        #pragma unroll
        for (int j = 0; j < 3; ++j)
            acc += (double)vv0[i][j].x * (double)w[j].x
                 + (double)vv0[i][j].y * (double)w[j].y;
        #pragma unroll
        for (int off = 32; off > 0; off >>= 1)
            acc += __shfl_xor(acc, off);
        int n = wbase + i;
        if (lane == 0 && n < NNODES) scores[n] = (float)acc;
    }

    // ---- Phase 2b: chunk-1 (batched loads, then dots) ----
    {
        float2 vv1[7][3];
        #pragma unroll
        for (int i = 0; i < 7; ++i) {
            int n  = wbase + 7 + i;
            int nn = n < NNODES ? n : NNODES - 1;
            const float2* row2 = (const float2*)(nodes + (size_t)nn * NC);
            #pragma unroll
            for (int j = 0; j < 3; ++j) vv1[i][j] = row2[lane + 64 * j];
        }
        #pragma unroll
        for (int i = 0; i < 7; ++i) {
            double acc = 0.0;
            #pragma unroll
            for (int j = 0; j < 3; ++j)
                acc += (double)vv1[i][j].x * (double)w[j].x
                     + (double)vv1[i][j].y * (double)w[j].y;
            #pragma unroll
            for (int off = 32; off > 0; off >>= 1)
                acc += __shfl_xor(acc, off);
            int n = wbase + 7 + i;
            if (lane == 0 && n < NNODES) scores[n] = (float)acc;
        }
    }
    __syncthreads();

    // ---- Phase 3: stable ascending rank; keep ranks >= START ----
    if (tid < NNODES) {
        const float s = scores[tid];
        int rank = 0;
        for (int m = 0; m < NNODES; ++m) {
            const float sm = scores[m];
            rank += (sm < s) || (sm == s && m < tid);   // stable tie-break
        }
        if (rank >= START) sel[rank - START] = tid;
    }
    __syncthreads();

    // ---- Phase 4: write output rows (float4, coalesced) ----
    {
        const int jg = tid / C4;                  // 0..9
        const int c4 = tid % C4;
        const float4* nodes4 = (const float4*)nodes;
        const float4* cls4   = (const float4*)(x + (size_t)b * SEQ * NC);
        float4* out4         = (float4*)(out + (size_t)b * OUTROWS * NC);
        #pragma unroll
        for (int it = 0; it < 5; ++it) {
            int j = jg + 10 * it;                 // 0..49
            const float4* src = (j == 0) ? cls4 : (nodes4 + (size_t)sel[j - 1] * C4);
            out4[(size_t)j * C4 + c4] = src[c4];
        }
    }
}

extern "C" void kernel_launch(void* const* d_in, const int* in_sizes, int n_in,
                              void* d_out, int out_size, void* d_ws, size_t ws_size,
                              hipStream_t stream) {
    const float* x   = (const float*)d_in[0];
    const float* ea  = (const float*)d_in[1];
    float* out       = (float*)d_out;

    hipLaunchKernelGGL(pooling_block_kernel,
                       dim3(NB), dim3(NT), 0, stream,
                       x, ea, out);
}